// Round 13
// baseline (268.042 us; speedup 1.0000x reference)
//
#include <hip/hip_runtime.h>
#include <hip/hip_bf16.h>
#include <math.h>

// Problem constants
#define B_   32
#define N_   2248
#define C_   1024
#define D_   128
#define P_   200
#define T_   2048            // N_ - P_
#define M_   (B_ * N_)       // 71936 rows total
#define SCALE_ 0.08838834764831845f  // D^-0.5

typedef __bf16 bf16;
typedef __bf16 bf16x8 __attribute__((ext_vector_type(8)));
typedef __bf16 bf16x4 __attribute__((ext_vector_type(4)));
typedef float  f32x4  __attribute__((ext_vector_type(4)));
typedef unsigned int u32x4 __attribute__((ext_vector_type(4)));

// V-transpose LDS column swizzle (attn)
#define VT_COL(dd, t) ((((((t) >> 3) ^ (((dd) >> 3) & 7)) << 3)) | ((t) & 7))

// direct-to-LDS 16B async copy (no VGPR round-trip)
__device__ __forceinline__ void gl_lds16(const void* g, void* l) {
    __builtin_amdgcn_global_load_lds(
        (const __attribute__((address_space(1))) unsigned int*)g,
        (__attribute__((address_space(3))) unsigned int*)l,
        16, 0, 0);
}

// ---------------------------------------------------------------------------
// Kernel 0: one-time weight transpose + bf16 convert.
// ---------------------------------------------------------------------------
__global__ void k_prep(const float* __restrict__ Wd, const float* __restrict__ Wu,
                       bf16* __restrict__ WtD, bf16* __restrict__ WtU) {
    int i = blockIdx.x * 256 + threadIdx.x;
    if (i >= 131072) return;
    int d = i >> 10, k = i & 1023;
    WtD[i] = (bf16)Wd[k * 128 + d];
    int c = i >> 7, e = i & 127;
    WtU[i] = (bf16)Wu[e * 1024 + c];
}

// ---------------------------------------------------------------------------
// Kernel A: down = gelu(x @ W_down + b_down).  T3+T4 ring-3 (r10-proven)
// rescaled to a 128x128 tile: slot = A 16KB + B 8KB = 24KB, ring 72KB,
// 2 blocks/CU. Per iter: 6 gl_lds/wave, 16 MFMA/wave -> 1.5x fewer barriers
// per staged byte than r10, half the B L2 traffic. grid = 562 (one round).
//   iter t: vmcnt(6) [tile t landed; t+1,t+2 in flight] -> raw s_barrier ->
//           STAGE(t+2) into slot (t+2)%3 -> compute tile t.
// ---------------------------------------------------------------------------
__launch_bounds__(256, 2)
__global__ void k_down(const float* __restrict__ x, const bf16* __restrict__ WtD,
                       const float* __restrict__ bd, bf16* __restrict__ down) {
    __shared__ __align__(16) char ring[3][24576];   // A @0 (16KB), B @16384 (8KB)
    const int tid = threadIdx.x;
    const int lane = tid & 63, w = tid >> 6;
    const int wm = w >> 1, wn = w & 1;
    const int li = lane & 15, lg = lane >> 4;
    const int m0 = blockIdx.x * 128;

    // A: 16 groups of 1KB (8 rows x 8 chunks); wave w owns groups 4w..4w+3.
    // dest pos lane&7 holds logical chunk (lane&7)^(row&7) -> src pre-swizzled.
    const float* asrc[4];
    int ag[4];
#pragma unroll
    for (int j = 0; j < 4; j++) {
        ag[j] = w * 4 + j;
        int row = ag[j] * 8 + (lane >> 3);
        asrc[j] = x + (size_t)(m0 + row) * C_ + ((((lane & 7) ^ (row & 7)) * 16) >> 2);
    }
    // B: 8 groups of 1KB (16 rows x 4 chunks); wave w owns groups 2w, 2w+1.
    const bf16* bsrc[2];
    int bg[2];
#pragma unroll
    for (int j = 0; j < 2; j++) {
        bg[j] = w * 2 + j;
        int row = bg[j] * 16 + (lane >> 2);
        bsrc[j] = WtD + (size_t)row * C_ + (((lane & 3) ^ (row & 3)) * 8);
    }

#define STAGE_(t_, s_) do {                                               \
        gl_lds16(asrc[0] + (t_) * 32, ring[s_] + ag[0] * 1024);           \
        gl_lds16(asrc[1] + (t_) * 32, ring[s_] + ag[1] * 1024);           \
        gl_lds16(asrc[2] + (t_) * 32, ring[s_] + ag[2] * 1024);           \
        gl_lds16(asrc[3] + (t_) * 32, ring[s_] + ag[3] * 1024);           \
        gl_lds16(bsrc[0] + (t_) * 32, ring[s_] + 16384 + bg[0] * 1024);   \
        gl_lds16(bsrc[1] + (t_) * 32, ring[s_] + 16384 + bg[1] * 1024);   \
    } while (0)

    f32x4 acc[4][4];
    const f32x4 zero = {0.f, 0.f, 0.f, 0.f};
#pragma unroll
    for (int i = 0; i < 4; i++)
#pragma unroll
        for (int j = 0; j < 4; j++) acc[i][j] = zero;

    STAGE_(0, 0);
    STAGE_(1, 1);

    for (int t = 0; t < 32; t++) {
        if (t < 31) { asm volatile("s_waitcnt vmcnt(6)" ::: "memory"); }
        else        { asm volatile("s_waitcnt vmcnt(0)" ::: "memory"); }
        __builtin_amdgcn_sched_barrier(0);
        __builtin_amdgcn_s_barrier();          // raw: no vmcnt(0) drain
        __builtin_amdgcn_sched_barrier(0);
        if (t + 2 < 32) {
            STAGE_(t + 2, (t + 2) % 3);
        }
        const char* sa = ring[t % 3];
        const char* sb = sa + 16384;
        // A fragments: row wm*64 + f*16 + li (f32, cvt to bf16)
        bf16x8 af[4];
#pragma unroll
        for (int f = 0; f < 4; f++) {
            int row = wm * 64 + f * 16 + li;
            const char* rb = sa + row * 128;
            int p0 = (2 * lg) ^ (row & 7), p1 = (2 * lg + 1) ^ (row & 7);
            f32x4 a0 = *(const f32x4*)(rb + p0 * 16);
            f32x4 a1 = *(const f32x4*)(rb + p1 * 16);
            bf16x8 o;
            o[0] = (bf16)a0[0]; o[1] = (bf16)a0[1]; o[2] = (bf16)a0[2]; o[3] = (bf16)a0[3];
            o[4] = (bf16)a1[0]; o[5] = (bf16)a1[1]; o[6] = (bf16)a1[2]; o[7] = (bf16)a1[3];
            af[f] = o;
        }
        // B fragments: row wn*64 + f*16 + li (bf16 direct)
        bf16x8 bfr[4];
#pragma unroll
        for (int f = 0; f < 4; f++) {
            int row = wn * 64 + f * 16 + li;
            bfr[f] = *(const bf16x8*)(sb + row * 64 + ((lg ^ (row & 3)) * 16));
        }
#pragma unroll
        for (int fm = 0; fm < 4; fm++)
#pragma unroll
            for (int fn = 0; fn < 4; fn++)
                acc[fm][fn] = __builtin_amdgcn_mfma_f32_16x16x32_bf16(
                    af[fm], bfr[fn], acc[fm][fn], 0, 0, 0);
    }
#undef STAGE_

    // epilogue: bias + exact gelu, store bf16
#pragma unroll
    for (int fn = 0; fn < 4; fn++) {
        int col = wn * 64 + fn * 16 + li;
        float bias = bd[col];
#pragma unroll
        for (int fm = 0; fm < 4; fm++) {
            int rb = m0 + wm * 64 + fm * 16 + lg * 4;
#pragma unroll
            for (int r = 0; r < 4; r++) {
                float v = acc[fm][fn][r] + bias;
                float g = 0.5f * v * (1.0f + erff(v * 0.70710678118654752f));
                down[(size_t)(rb + r) * D_ + col] = (bf16)g;
            }
        }
    }
}

// ---------------------------------------------------------------------------
// Kernel F: FUSED split-4 attention + token-row up-GEMM. UNCHANGED from r12
// (proven: 221.9 total). Attn blocks first -> overlap with the up stream.
// ---------------------------------------------------------------------------
__launch_bounds__(256, 3)
__global__ void k_fused(const bf16* __restrict__ down, float* __restrict__ Opart,
                        float* __restrict__ Mpart, float* __restrict__ Lpart,
                        const bf16* __restrict__ WtU, const float* __restrict__ bu,
                        const float* __restrict__ gate, float* __restrict__ out) {
    __shared__ bf16 Ks[64][136];
    __shared__ bf16 Vt[128][72];
    __shared__ bf16 Ps[4][16][72];
    const int tid = threadIdx.x;
    const int lane = tid & 63, w = tid >> 6;
    const int li = lane & 15, lg = lane >> 4;

    if (blockIdx.x < 512) {
        // ---------------- attention path (split-4) ----------------
        const int bid = blockIdx.x;
        const int wg = (bid & 7) * 64 + (bid >> 3);   // XCD swizzle (512%8==0)
        const int b  = wg >> 4;
        const int qt = (wg >> 2) & 3;
        const int th = wg & 3;
        const size_t base = (size_t)b * N_ * D_;
        const int tbase = P_ + th * 512;

        bf16x8 qf[4];
#pragma unroll
        for (int kk = 0; kk < 4; kk++)
            qf[kk] = *(const bf16x8*)(down + base +
                        (size_t)(qt * 64 + w * 16 + li) * D_ + kk * 32 + lg * 8);

        float m_run[4], l_run[4];
        f32x4 acc[8];
        const f32x4 zero = {0.f, 0.f, 0.f, 0.f};
#pragma unroll
        for (int r = 0; r < 4; r++) { m_run[r] = -3.0e38f; l_run[r] = 0.f; }
#pragma unroll
        for (int fn = 0; fn < 8; fn++) acc[fn] = zero;

        for (int tt = 0; tt < 8; tt++) {
            __syncthreads();
#pragma unroll
            for (int it = 0; it < 4; it++) {
                int ch = tid + it * 256;
                int r = ch >> 4, c8 = (ch & 15) * 8;
                u32x4 v = *(const u32x4*)(down + base +
                              (size_t)(tbase + tt * 64 + r) * D_ + c8);
                *(u32x4*)&Ks[r][c8] = v;
                bf16 tmp[8];
                *(u32x4*)tmp = v;
#pragma unroll
                for (int j = 0; j < 8; j++) Vt[c8 + j][VT_COL(c8 + j, r)] = tmp[j];
            }
            __syncthreads();
            f32x4 s[4];
#pragma unroll
            for (int fn = 0; fn < 4; fn++) {
                s[fn] = zero;
#pragma unroll
                for (int kk = 0; kk < 4; kk++) {
                    bf16x8 kf = *(const bf16x8*)&Ks[fn * 16 + li][kk * 32 + lg * 8];
                    s[fn] = __builtin_amdgcn_mfma_f32_16x16x32_bf16(qf[kk], kf, s[fn], 0, 0, 0);
                }
                s[fn] *= SCALE_;
            }
#pragma unroll
            for (int r = 0; r < 4; r++) {
                float tmax = fmaxf(fmaxf(s[0][r], s[1][r]), fmaxf(s[2][r], s[3][r]));
#pragma unroll
                for (int off = 1; off < 16; off <<= 1)
                    tmax = fmaxf(tmax, __shfl_xor(tmax, off, 64));
                float mnew = fmaxf(m_run[r], tmax);
                float corr = __expf(m_run[r] - mnew);
                m_run[r] = mnew;
                float psum = 0.f;
#pragma unroll
                for (int fn = 0; fn < 4; fn++) {
                    float p = __expf(s[fn][r] - mnew);
                    psum += p;
                    Ps[w][lg * 4 + r][fn * 16 + li] = (bf16)p;
                }
#pragma unroll
                for (int off = 1; off < 16; off <<= 1)
                    psum += __shfl_xor(psum, off, 64);
                l_run[r] = l_run[r] * corr + psum;
#pragma unroll
                for (int fn = 0; fn < 8; fn++) acc[fn][r] *= corr;
            }
#pragma unroll
            for (int kk = 0; kk < 2; kk++) {
                bf16x8 pf = *(const bf16x8*)&Ps[w][li][kk * 32 + lg * 8];
#pragma unroll
                for (int fn = 0; fn < 8; fn++) {
                    int d = fn * 16 + li;
                    bf16x8 vf = *(const bf16x8*)&Vt[d][VT_COL(d, kk * 32 + lg * 8)];
                    acc[fn] = __builtin_amdgcn_mfma_f32_16x16x32_bf16(pf, vf, acc[fn], 0, 0, 0);
                }
            }
        }
#pragma unroll
        for (int r = 0; r < 4; r++) {
            int q = qt * 64 + w * 16 + lg * 4 + r;
            size_t ro = ((size_t)(b * 4 + th) * 256 + q) * 128;
#pragma unroll
            for (int fn = 0; fn < 8; fn++)
                Opart[ro + fn * 16 + li] = acc[fn][r];
            if (li == 0) {
                Mpart[(b * 4 + th) * 256 + q] = m_run[r];
                Lpart[(b * 4 + th) * 256 + q] = l_run[r];
            }
        }
    } else {
        // ---------------- token-row up-GEMM path ----------------
        const int wm = w >> 1, wn = w & 1;
        int bidu = blockIdx.x - 512;                 // 0..4095
        int wg = (bidu & 7) * 512 + (bidu >> 3);     // bijective XCD swizzle
        const int b  = wg >> 7;
        const int rt = (wg >> 3) & 15;
        const int nt = wg & 7;
        const size_t m0 = (size_t)b * N_ + P_ + rt * 128;
        const int n0 = nt * 128;

        const bf16* Bp = WtU + (size_t)(n0 + wn * 64 + li) * D_ + lg * 8;

        f32x4 acc[4][4];
        const f32x4 zero = {0.f, 0.f, 0.f, 0.f};
#pragma unroll
        for (int i = 0; i < 4; i++)
#pragma unroll
            for (int j = 0; j < 4; j++) acc[i][j] = zero;

#pragma unroll
        for (int kk = 0; kk < 4; kk++) {
            bf16x8 af[4], bf_[4];
#pragma unroll
            for (int f = 0; f < 4; f++) {
                af[f]  = *(const bf16x8*)(down + (m0 + wm * 64 + f * 16 + li) * D_ + kk * 32 + lg * 8);
                bf_[f] = *(const bf16x8*)(Bp + (size_t)(f * 16) * D_ + kk * 32);
            }
#pragma unroll
            for (int fm = 0; fm < 4; fm++)
#pragma unroll
                for (int fn = 0; fn < 4; fn++)
                    acc[fm][fn] = __builtin_amdgcn_mfma_f32_16x16x32_bf16(
                        af[fm], bf_[fn], acc[fm][fn], 0, 0, 0);
        }

        float g = gate[0];
#pragma unroll
        for (int fn = 0; fn < 4; fn++) {
            int c = n0 + wn * 64 + fn * 16 + li;
            float bias = bu[c];
#pragma unroll
            for (int fm = 0; fm < 4; fm++) {
                size_t rb = m0 + wm * 64 + fm * 16 + lg * 4;
#pragma unroll
                for (int r = 0; r < 4; r++)
                    out[(rb + r) * C_ + c] = g * (acc[fm][fn][r] + bias);
            }
        }
    }
}

// ---------------------------------------------------------------------------
// Kernel C2: up-GEMM on PROMPT rows with FUSED partial-combine.
// Builds the combined-O A-fragments from Opart/Mpart/Lpart in-register
// (per kk-step), so k_comb and the pout buffer are deleted. grid = 32x2x8.
// ---------------------------------------------------------------------------
__launch_bounds__(256, 2)
__global__ void k_up_prompt(const float* __restrict__ Opart, const float* __restrict__ Mpart,
                            const float* __restrict__ Lpart, const bf16* __restrict__ WtU,
                            const float* __restrict__ bu, const float* __restrict__ gate,
                            float* __restrict__ out) {
    const int tid = threadIdx.x;
    const int lane = tid & 63, wid = tid >> 6;
    const int wm = wid >> 1, wn = wid & 1;
    const int li = lane & 15, lg = lane >> 4;
    const int b  = blockIdx.x >> 4;
    const int pt = (blockIdx.x >> 3) & 1;
    const int nt = blockIdx.x & 7;
    const int n0 = nt * 128;

    // per-row combine weights (4 rows per thread, one per fm fragment)
    int qrow[4];
    float aw[4][4], inv[4];
#pragma unroll
    for (int f = 0; f < 4; f++) {
        int n = pt * 128 + wm * 64 + f * 16 + li;
        qrow[f] = n < P_ ? n : P_ - 1;           // clamp loads; stores masked
        float mm[4], ll[4], m = -3.0e38f;
#pragma unroll
        for (int t = 0; t < 4; t++) {
            mm[t] = Mpart[(b * 4 + t) * 256 + qrow[f]];
            ll[t] = Lpart[(b * 4 + t) * 256 + qrow[f]];
            m = fmaxf(m, mm[t]);
        }
        float lsum = 0.f;
#pragma unroll
        for (int t = 0; t < 4; t++) { aw[f][t] = __expf(mm[t] - m); lsum += ll[t] * aw[f][t]; }
        inv[f] = 1.0f / lsum;
    }
    const bf16* Bp = WtU + (size_t)(n0 + wn * 64 + li) * D_ + lg * 8;

    f32x4 acc[4][4];
    const f32x4 zero = {0.f, 0.f, 0.f, 0.f};
#pragma unroll
    for (int i = 0; i < 4; i++)
#pragma unroll
        for (int j = 0; j < 4; j++) acc[i][j] = zero;

#pragma unroll
    for (int kk = 0; kk < 4; kk++) {
        bf16x8 af[4], bf_[4];
#pragma unroll
        for (int f = 0; f < 4; f++) {
            f32x4 o0 = zero, o1 = zero;
#pragma unroll
            for (int t = 0; t < 4; t++) {
                const float* op = Opart + ((size_t)(b * 4 + t) * 256 + qrow[f]) * 128
                                  + kk * 32 + lg * 8;
                f32x4 v0 = *(const f32x4*)op;
                f32x4 v1 = *(const f32x4*)(op + 4);
#pragma unroll
                for (int j = 0; j < 4; j++) { o0[j] += v0[j] * aw[f][t]; o1[j] += v1[j] * aw[f][t]; }
            }
            bf16x8 o;
#pragma unroll
            for (int j = 0; j < 4; j++) { o[j] = (bf16)(o0[j] * inv[f]); o[j + 4] = (bf16)(o1[j] * inv[f]); }
            af[f] = o;
            bf_[f] = *(const bf16x8*)(Bp + (size_t)(f * 16) * D_ + kk * 32);
        }
#pragma unroll
        for (int fm = 0; fm < 4; fm++)
#pragma unroll
            for (int fn = 0; fn < 4; fn++)
                acc[fm][fn] = __builtin_amdgcn_mfma_f32_16x16x32_bf16(
                    af[fm], bf_[fn], acc[fm][fn], 0, 0, 0);
    }

    float g = gate[0];
#pragma unroll
    for (int fn = 0; fn < 4; fn++) {
        int c = n0 + wn * 64 + fn * 16 + li;
        float bias = bu[c];
#pragma unroll
        for (int fm = 0; fm < 4; fm++) {
            int nr = pt * 128 + wm * 64 + fm * 16 + lg * 4;
#pragma unroll
            for (int r = 0; r < 4; r++) {
                if (nr + r < P_)
                    out[((size_t)b * N_ + nr + r) * C_ + c] = g * (acc[fm][fn][r] + bias);
            }
        }
    }
}

// ---------------------------------------------------------------------------
extern "C" void kernel_launch(void* const* d_in, const int* in_sizes, int n_in,
                              void* d_out, int out_size, void* d_ws, size_t ws_size,
                              hipStream_t stream) {
    const float* x    = (const float*)d_in[0];
    const float* Wd   = (const float*)d_in[1];
    const float* bd   = (const float*)d_in[2];
    const float* Wu   = (const float*)d_in[3];
    const float* bu   = (const float*)d_in[4];
    const float* gate = (const float*)d_in[5];
    float* out = (float*)d_out;

    char* w = (char*)d_ws;
    bf16*  down  = (bf16*)w;                          // 18,415,616 B
    bf16*  WtD   = (bf16*)(w + 18415616);             // 262,144 B
    bf16*  WtU   = (bf16*)(w + 18677760);             // 262,144 B
    float* Opart = (float*)(w + 18939904);            // 16,777,216 B
    float* Mpart = (float*)(w + 35717120);            // 131,072 B
    float* Lpart = (float*)(w + 35848192);            // 131,072 B  (~36 MB)

    k_prep<<<512, 256, 0, stream>>>(Wd, Wu, WtD, WtU);
    k_down<<<M_ / 128, 256, 0, stream>>>(x, WtD, bd, down);             // 562 blocks
    k_fused<<<512 + 4096, 256, 0, stream>>>(down, Opart, Mpart, Lpart,
                                            WtU, bu, gate, out);
    k_up_prompt<<<512, 256, 0, stream>>>(Opart, Mpart, Lpart, WtU, bu, gate, out);
}

// Round 14
// 219.543 us; speedup vs baseline: 1.2209x; 1.2209x over previous
//
#include <hip/hip_runtime.h>
#include <hip/hip_bf16.h>
#include <math.h>

// Problem constants
#define B_   32
#define N_   2248
#define C_   1024
#define D_   128
#define P_   200
#define T_   2048            // N_ - P_
#define M_   (B_ * N_)       // 71936 rows total
#define SCALE_ 0.08838834764831845f  // D^-0.5

typedef __bf16 bf16;
typedef __bf16 bf16x8 __attribute__((ext_vector_type(8)));
typedef __bf16 bf16x4 __attribute__((ext_vector_type(4)));
typedef float  f32x4  __attribute__((ext_vector_type(4)));
typedef unsigned int u32x4 __attribute__((ext_vector_type(4)));

// V-transpose LDS column swizzle (attn)
#define VT_COL(dd, t) ((((((t) >> 3) ^ (((dd) >> 3) & 7)) << 3)) | ((t) & 7))

// direct-to-LDS 16B async copy (no VGPR round-trip)
__device__ __forceinline__ void gl_lds16(const void* g, void* l) {
    __builtin_amdgcn_global_load_lds(
        (const __attribute__((address_space(1))) unsigned int*)g,
        (__attribute__((address_space(3))) unsigned int*)l,
        16, 0, 0);
}

// ---------------------------------------------------------------------------
// Kernel 0: one-time weight transpose + bf16 convert.
// ---------------------------------------------------------------------------
__global__ void k_prep(const float* __restrict__ Wd, const float* __restrict__ Wu,
                       bf16* __restrict__ WtD, bf16* __restrict__ WtU) {
    int i = blockIdx.x * 256 + threadIdx.x;
    if (i >= 131072) return;
    int d = i >> 10, k = i & 1023;
    WtD[i] = (bf16)Wd[k * 128 + d];
    int c = i >> 7, e = i & 127;
    WtU[i] = (bf16)Wu[e * 1024 + c];
}

// ---------------------------------------------------------------------------
// Kernel A: down = gelu(x @ W_down + b_down).  T3+T4 ring-3 (r10-proven
// schedule) widened to 512-thread blocks: 8 waves/block, 3 blocks/CU ->
// 24 waves/CU (vs r10's 12). Wave-BW scaling model (r4/r13: 8w ~1.0,
// r10: 12w ~2.45, fill: 32w ~6.7 TB/s) predicts ~4.5 TB/s.
// Tile 64x128, BK=32. Wave w: rows (w>>2)*32..+31, cols (w&3)*32..+31.
// Per iter/wave: 2 gl_lds (1 A + 1 B, counted vmcnt(2)), 4 MFMA.
//   iter t: vmcnt(2) [tile t landed; t+1 in flight] -> raw s_barrier ->
//           STAGE(t+2) into slot (t+2)%3 -> compute tile t.
// ---------------------------------------------------------------------------
__launch_bounds__(512, 6)
__global__ void k_down(const float* __restrict__ x, const bf16* __restrict__ WtD,
                       const float* __restrict__ bd, bf16* __restrict__ down) {
    __shared__ __align__(16) char ring[3][16384];   // A @0 (8KB), B @8192 (8KB)
    const int tid = threadIdx.x;
    const int lane = tid & 63, w = tid >> 6;        // w: 0..7
    const int wm = w >> 2, wn = w & 3;
    const int li = lane & 15, lg = lane >> 4;
    const int m0 = blockIdx.x * 64;

    // A: 8 wave-chunks of 1KB (8 rows x 8 x 16B); wave w owns chunk w.
    // LDS dest is linear (lane*16); global src col pre-swizzled (rule #21).
    const int arow = w * 8 + (lane >> 3);
    const float* asrc = x + (size_t)(m0 + arow) * C_ +
                        ((((lane & 7) ^ (arow & 7)) * 16) >> 2);
    // B: 8 wave-chunks of 1KB (16 rows x 4 x 16B); wave w owns chunk w.
    const int brow = w * 16 + (lane >> 2);
    const bf16* bsrc = WtD + (size_t)brow * C_ + (((lane & 3) ^ (brow & 3)) * 8);

#define STAGE_(t_, s_) do {                                       \
        gl_lds16(asrc + (t_) * 32, ring[s_] + w * 1024);          \
        gl_lds16(bsrc + (t_) * 32, ring[s_] + 8192 + w * 1024);   \
    } while (0)

    f32x4 acc[2][2];
    const f32x4 zero = {0.f, 0.f, 0.f, 0.f};
#pragma unroll
    for (int i = 0; i < 2; i++)
#pragma unroll
        for (int j = 0; j < 2; j++) acc[i][j] = zero;

    STAGE_(0, 0);
    STAGE_(1, 1);

    for (int t = 0; t < 32; t++) {
        if (t < 31) { asm volatile("s_waitcnt vmcnt(2)" ::: "memory"); }
        else        { asm volatile("s_waitcnt vmcnt(0)" ::: "memory"); }
        __builtin_amdgcn_sched_barrier(0);
        __builtin_amdgcn_s_barrier();          // raw: no vmcnt(0) drain
        __builtin_amdgcn_sched_barrier(0);
        if (t + 2 < 32) {
            STAGE_(t + 2, (t + 2) % 3);
        }
        const char* sa = ring[t % 3];
        const char* sb = sa + 8192;
        // A fragments: row wm*32 + f*16 + li (f32, swizzled read, cvt->bf16)
        bf16x8 af[2];
#pragma unroll
        for (int f = 0; f < 2; f++) {
            int row = wm * 32 + f * 16 + li;
            const char* rb = sa + row * 128;
            int p0 = (2 * lg) ^ (row & 7), p1 = (2 * lg + 1) ^ (row & 7);
            f32x4 a0 = *(const f32x4*)(rb + p0 * 16);
            f32x4 a1 = *(const f32x4*)(rb + p1 * 16);
            bf16x8 o;
            o[0] = (bf16)a0[0]; o[1] = (bf16)a0[1]; o[2] = (bf16)a0[2]; o[3] = (bf16)a0[3];
            o[4] = (bf16)a1[0]; o[5] = (bf16)a1[1]; o[6] = (bf16)a1[2]; o[7] = (bf16)a1[3];
            af[f] = o;
        }
        // B fragments: row wn*32 + f*16 + li (bf16, swizzled read)
        bf16x8 bfr[2];
#pragma unroll
        for (int f = 0; f < 2; f++) {
            int row = wn * 32 + f * 16 + li;
            bfr[f] = *(const bf16x8*)(sb + row * 64 + ((lg ^ (row & 3)) * 16));
        }
#pragma unroll
        for (int fm = 0; fm < 2; fm++)
#pragma unroll
            for (int fn = 0; fn < 2; fn++)
                acc[fm][fn] = __builtin_amdgcn_mfma_f32_16x16x32_bf16(
                    af[fm], bfr[fn], acc[fm][fn], 0, 0, 0);
    }
#undef STAGE_

    // epilogue: bias + exact gelu, store bf16
#pragma unroll
    for (int fn = 0; fn < 2; fn++) {
        int col = wn * 32 + fn * 16 + li;
        float bias = bd[col];
#pragma unroll
        for (int fm = 0; fm < 2; fm++) {
            int rb = m0 + wm * 32 + fm * 16 + lg * 4;
#pragma unroll
            for (int r = 0; r < 4; r++) {
                float v = acc[fm][fn][r] + bias;
                float g = 0.5f * v * (1.0f + erff(v * 0.70710678118654752f));
                down[(size_t)(rb + r) * D_ + col] = (bf16)g;
            }
        }
    }
}

// ---------------------------------------------------------------------------
// Kernel F: FUSED split-4 attention + token-row up-GEMM. UNCHANGED from r12
// (proven: 221.9 total). Attn blocks first -> overlap with the up stream.
// ---------------------------------------------------------------------------
__launch_bounds__(256, 3)
__global__ void k_fused(const bf16* __restrict__ down, float* __restrict__ Opart,
                        float* __restrict__ Mpart, float* __restrict__ Lpart,
                        const bf16* __restrict__ WtU, const float* __restrict__ bu,
                        const float* __restrict__ gate, float* __restrict__ out) {
    __shared__ bf16 Ks[64][136];
    __shared__ bf16 Vt[128][72];
    __shared__ bf16 Ps[4][16][72];
    const int tid = threadIdx.x;
    const int lane = tid & 63, w = tid >> 6;
    const int li = lane & 15, lg = lane >> 4;

    if (blockIdx.x < 512) {
        // ---------------- attention path (split-4) ----------------
        const int bid = blockIdx.x;
        const int wg = (bid & 7) * 64 + (bid >> 3);   // XCD swizzle (512%8==0)
        const int b  = wg >> 4;
        const int qt = (wg >> 2) & 3;
        const int th = wg & 3;
        const size_t base = (size_t)b * N_ * D_;
        const int tbase = P_ + th * 512;

        bf16x8 qf[4];
#pragma unroll
        for (int kk = 0; kk < 4; kk++)
            qf[kk] = *(const bf16x8*)(down + base +
                        (size_t)(qt * 64 + w * 16 + li) * D_ + kk * 32 + lg * 8);

        float m_run[4], l_run[4];
        f32x4 acc[8];
        const f32x4 zero = {0.f, 0.f, 0.f, 0.f};
#pragma unroll
        for (int r = 0; r < 4; r++) { m_run[r] = -3.0e38f; l_run[r] = 0.f; }
#pragma unroll
        for (int fn = 0; fn < 8; fn++) acc[fn] = zero;

        for (int tt = 0; tt < 8; tt++) {
            __syncthreads();
#pragma unroll
            for (int it = 0; it < 4; it++) {
                int ch = tid + it * 256;
                int r = ch >> 4, c8 = (ch & 15) * 8;
                u32x4 v = *(const u32x4*)(down + base +
                              (size_t)(tbase + tt * 64 + r) * D_ + c8);
                *(u32x4*)&Ks[r][c8] = v;
                bf16 tmp[8];
                *(u32x4*)tmp = v;
#pragma unroll
                for (int j = 0; j < 8; j++) Vt[c8 + j][VT_COL(c8 + j, r)] = tmp[j];
            }
            __syncthreads();
            f32x4 s[4];
#pragma unroll
            for (int fn = 0; fn < 4; fn++) {
                s[fn] = zero;
#pragma unroll
                for (int kk = 0; kk < 4; kk++) {
                    bf16x8 kf = *(const bf16x8*)&Ks[fn * 16 + li][kk * 32 + lg * 8];
                    s[fn] = __builtin_amdgcn_mfma_f32_16x16x32_bf16(qf[kk], kf, s[fn], 0, 0, 0);
                }
                s[fn] *= SCALE_;
            }
#pragma unroll
            for (int r = 0; r < 4; r++) {
                float tmax = fmaxf(fmaxf(s[0][r], s[1][r]), fmaxf(s[2][r], s[3][r]));
#pragma unroll
                for (int off = 1; off < 16; off <<= 1)
                    tmax = fmaxf(tmax, __shfl_xor(tmax, off, 64));
                float mnew = fmaxf(m_run[r], tmax);
                float corr = __expf(m_run[r] - mnew);
                m_run[r] = mnew;
                float psum = 0.f;
#pragma unroll
                for (int fn = 0; fn < 4; fn++) {
                    float p = __expf(s[fn][r] - mnew);
                    psum += p;
                    Ps[w][lg * 4 + r][fn * 16 + li] = (bf16)p;
                }
#pragma unroll
                for (int off = 1; off < 16; off <<= 1)
                    psum += __shfl_xor(psum, off, 64);
                l_run[r] = l_run[r] * corr + psum;
#pragma unroll
                for (int fn = 0; fn < 8; fn++) acc[fn][r] *= corr;
            }
#pragma unroll
            for (int kk = 0; kk < 2; kk++) {
                bf16x8 pf = *(const bf16x8*)&Ps[w][li][kk * 32 + lg * 8];
#pragma unroll
                for (int fn = 0; fn < 8; fn++) {
                    int d = fn * 16 + li;
                    bf16x8 vf = *(const bf16x8*)&Vt[d][VT_COL(d, kk * 32 + lg * 8)];
                    acc[fn] = __builtin_amdgcn_mfma_f32_16x16x32_bf16(pf, vf, acc[fn], 0, 0, 0);
                }
            }
        }
#pragma unroll
        for (int r = 0; r < 4; r++) {
            int q = qt * 64 + w * 16 + lg * 4 + r;
            size_t ro = ((size_t)(b * 4 + th) * 256 + q) * 128;
#pragma unroll
            for (int fn = 0; fn < 8; fn++)
                Opart[ro + fn * 16 + li] = acc[fn][r];
            if (li == 0) {
                Mpart[(b * 4 + th) * 256 + q] = m_run[r];
                Lpart[(b * 4 + th) * 256 + q] = l_run[r];
            }
        }
    } else {
        // ---------------- token-row up-GEMM path ----------------
        const int wm = w >> 1, wn = w & 1;
        int bidu = blockIdx.x - 512;                 // 0..4095
        int wg = (bidu & 7) * 512 + (bidu >> 3);     // bijective XCD swizzle
        const int b  = wg >> 7;
        const int rt = (wg >> 3) & 15;
        const int nt = wg & 7;
        const size_t m0 = (size_t)b * N_ + P_ + rt * 128;
        const int n0 = nt * 128;

        const bf16* Bp = WtU + (size_t)(n0 + wn * 64 + li) * D_ + lg * 8;

        f32x4 acc[4][4];
        const f32x4 zero = {0.f, 0.f, 0.f, 0.f};
#pragma unroll
        for (int i = 0; i < 4; i++)
#pragma unroll
            for (int j = 0; j < 4; j++) acc[i][j] = zero;

#pragma unroll
        for (int kk = 0; kk < 4; kk++) {
            bf16x8 af[4], bf_[4];
#pragma unroll
            for (int f = 0; f < 4; f++) {
                af[f]  = *(const bf16x8*)(down + (m0 + wm * 64 + f * 16 + li) * D_ + kk * 32 + lg * 8);
                bf_[f] = *(const bf16x8*)(Bp + (size_t)(f * 16) * D_ + kk * 32);
            }
#pragma unroll
            for (int fm = 0; fm < 4; fm++)
#pragma unroll
                for (int fn = 0; fn < 4; fn++)
                    acc[fm][fn] = __builtin_amdgcn_mfma_f32_16x16x32_bf16(
                        af[fm], bf_[fn], acc[fm][fn], 0, 0, 0);
        }

        float g = gate[0];
#pragma unroll
        for (int fn = 0; fn < 4; fn++) {
            int c = n0 + wn * 64 + fn * 16 + li;
            float bias = bu[c];
#pragma unroll
            for (int fm = 0; fm < 4; fm++) {
                size_t rb = m0 + wm * 64 + fm * 16 + lg * 4;
#pragma unroll
                for (int r = 0; r < 4; r++)
                    out[(rb + r) * C_ + c] = g * (acc[fm][fn][r] + bias);
            }
        }
    }
}

// ---------------------------------------------------------------------------
// Kernel B2: combine the four token-quarter partials into pout (bf16).
// ---------------------------------------------------------------------------
__global__ void k_comb(const float* __restrict__ Opart, const float* __restrict__ Mpart,
                       const float* __restrict__ Lpart, bf16* __restrict__ pout) {
    int gid = blockIdx.x * 256 + threadIdx.x;
    if (gid >= (B_ * P_ * D_) / 4) return;
    int e = gid * 4;
    int row = e >> 7;
    int col = e & 127;
    int b = row / P_;
    int q = row - b * P_;
    float mm[4], ll[4];
    float m = -3.0e38f;
#pragma unroll
    for (int t = 0; t < 4; t++) {
        mm[t] = Mpart[(b * 4 + t) * 256 + q];
        ll[t] = Lpart[(b * 4 + t) * 256 + q];
        m = fmaxf(m, mm[t]);
    }
    float a[4], lsum = 0.f;
#pragma unroll
    for (int t = 0; t < 4; t++) { a[t] = __expf(mm[t] - m); lsum += ll[t] * a[t]; }
    float inv = 1.0f / lsum;
    f32x4 o = {0.f, 0.f, 0.f, 0.f};
#pragma unroll
    for (int t = 0; t < 4; t++) {
        f32x4 ot = *(const f32x4*)&Opart[((size_t)(b * 4 + t) * 256 + q) * 128 + col];
#pragma unroll
        for (int j = 0; j < 4; j++) o[j] += ot[j] * a[t];
    }
    bf16x4 ob;
#pragma unroll
    for (int j = 0; j < 4; j++) ob[j] = (bf16)(o[j] * inv);
    *(bf16x4*)&pout[(size_t)row * 128 + col] = ob;
}

// ---------------------------------------------------------------------------
// Kernel C2: up-GEMM on PROMPT rows (reads pout only). grid = 32 x 2 x 8.
// ---------------------------------------------------------------------------
__launch_bounds__(256, 3)
__global__ void k_up_prompt(const bf16* __restrict__ pout, const bf16* __restrict__ WtU,
                            const float* __restrict__ bu, const float* __restrict__ gate,
                            float* __restrict__ out) {
    const int tid = threadIdx.x;
    const int lane = tid & 63, wid = tid >> 6;
    const int wm = wid >> 1, wn = wid & 1;
    const int li = lane & 15, lg = lane >> 4;
    const int b  = blockIdx.x >> 4;
    const int pt = (blockIdx.x >> 3) & 1;
    const int nt = blockIdx.x & 7;
    const int n0 = nt * 128;

    const bf16* rp[4];
#pragma unroll
    for (int f = 0; f < 4; f++) {
        int n = pt * 128 + wm * 64 + f * 16 + li;
        int nc = n < P_ ? n : P_ - 1;            // clamp loads, stores masked
        rp[f] = pout + (size_t)(b * P_ + nc) * D_ + lg * 8;
    }
    const bf16* Bp = WtU + (size_t)(n0 + wn * 64 + li) * D_ + lg * 8;

    f32x4 acc[4][4];
    const f32x4 zero = {0.f, 0.f, 0.f, 0.f};
#pragma unroll
    for (int i = 0; i < 4; i++)
#pragma unroll
        for (int j = 0; j < 4; j++) acc[i][j] = zero;

#pragma unroll
    for (int kk = 0; kk < 4; kk++) {
        bf16x8 af[4], bf_[4];
#pragma unroll
        for (int f = 0; f < 4; f++) {
            af[f]  = *(const bf16x8*)(rp[f] + kk * 32);
            bf_[f] = *(const bf16x8*)(Bp + (size_t)(f * 16) * D_ + kk * 32);
        }
#pragma unroll
        for (int fm = 0; fm < 4; fm++)
#pragma unroll
            for (int fn = 0; fn < 4; fn++)
                acc[fm][fn] = __builtin_amdgcn_mfma_f32_16x16x32_bf16(
                    af[fm], bf_[fn], acc[fm][fn], 0, 0, 0);
    }

    float g = gate[0];
#pragma unroll
    for (int fn = 0; fn < 4; fn++) {
        int c = n0 + wn * 64 + fn * 16 + li;
        float bias = bu[c];
#pragma unroll
        for (int fm = 0; fm < 4; fm++) {
            int nr = pt * 128 + wm * 64 + fm * 16 + lg * 4;
#pragma unroll
            for (int r = 0; r < 4; r++) {
                if (nr + r < P_)
                    out[((size_t)b * N_ + nr + r) * C_ + c] = g * (acc[fm][fn][r] + bias);
            }
        }
    }
}

// ---------------------------------------------------------------------------
extern "C" void kernel_launch(void* const* d_in, const int* in_sizes, int n_in,
                              void* d_out, int out_size, void* d_ws, size_t ws_size,
                              hipStream_t stream) {
    const float* x    = (const float*)d_in[0];
    const float* Wd   = (const float*)d_in[1];
    const float* bd   = (const float*)d_in[2];
    const float* Wu   = (const float*)d_in[3];
    const float* bu   = (const float*)d_in[4];
    const float* gate = (const float*)d_in[5];
    float* out = (float*)d_out;

    char* w = (char*)d_ws;
    bf16*  down  = (bf16*)w;                          // 18,415,616 B
    bf16*  pout  = (bf16*)(w + 18415616);             // 1,638,400 B
    bf16*  WtD   = (bf16*)(w + 20054016);             // 262,144 B
    bf16*  WtU   = (bf16*)(w + 20316160);             // 262,144 B
    float* Opart = (float*)(w + 20578304);            // 16,777,216 B
    float* Mpart = (float*)(w + 37355520);            // 131,072 B
    float* Lpart = (float*)(w + 37486592);            // 131,072 B

    k_prep<<<512, 256, 0, stream>>>(Wd, Wu, WtD, WtU);
    k_down<<<M_ / 64, 512, 0, stream>>>(x, WtD, bd, down);              // 1124 blocks
    k_fused<<<512 + 4096, 256, 0, stream>>>(down, Opart, Mpart, Lpart,
                                            WtU, bu, gate, out);
    k_comb<<<800, 256, 0, stream>>>(Opart, Mpart, Lpart, pout);
    k_up_prompt<<<512, 256, 0, stream>>>(pout, WtU, bu, gate, out);
}